// Round 13
// baseline (68.963 us; speedup 1.0000x reference)
//
#include <hip/hip_runtime.h>
#include <stdint.h>

#define HID 768
#define HD  64
#define NB  8
#define SEQ 2048

typedef __bf16 bf16_t;
typedef __bf16 bf16x8 __attribute__((ext_vector_type(8)));
typedef __bf16 bf16x4 __attribute__((ext_vector_type(4)));
typedef float  f32x4  __attribute__((ext_vector_type(4)));
typedef int    i32x4  __attribute__((ext_vector_type(4)));

typedef const __attribute__((address_space(1))) uint32_t* gptr_t;
typedef __attribute__((address_space(3))) uint32_t* lptr_t;

// workspace layout (bytes)
#define WT_OFF 0                         // bf16 WT[3][64][768]
#define B_OFF  (3*HD*HID*2)              // f32  bias[3][64]
#define Q_OFF  (512*1024)                // bf16 q[16384][64]   (row-major)
#define K_OFF  (Q_OFF + NB*SEQ*HD*2)     // bf16 k[16384][64]   (row-major)
#define V_OFF  (K_OFF + NB*SEQ*HD*2)     // bf16 vt PANELS [8][32][64][64]
#define WS_NEED ((size_t)(V_OFF + NB*SEQ*HD*2))

#define ALPHA 0.18033688011112043f       // log2(e) / sqrt(64)

// ---------------- kernel 1: convert + transpose weights, fold scale ----------
__global__ __launch_bounds__(256) void cvt_kernel(
    const float* __restrict__ Wq, const float* __restrict__ bq,
    const float* __restrict__ Wk, const float* __restrict__ bk,
    const float* __restrict__ Wv, const float* __restrict__ bv,
    uint8_t* __restrict__ ws) {
  bf16_t* wt = (bf16_t*)(ws + WT_OFF);
  float*  bs = (float*)(ws + B_OFF);
  int idx = blockIdx.x * 256 + threadIdx.x;
  if (idx < 3 * HID * HD) {
    int n = idx & 63;
    int h = (idx >> 6) % HID;
    int t = idx / (HID * HD);
    const float* W = (t == 0) ? Wq : (t == 1) ? Wk : Wv;
    float v = W[h * HD + n];
    if (t == 0) v *= ALPHA;                    // prescale q path
    wt[(size_t)(t * HD + n) * HID + h] = (bf16_t)v;   // WT[t][n][h]
  }
  if (idx < 3 * HD) {
    int t = idx / HD, n = idx % HD;
    const float* bsrc = (t == 0) ? bq : (t == 1) ? bk : bv;
    bs[idx] = bsrc[n] * ((t == 0) ? ALPHA : 1.0f);
  }
}

// ---------------- kernel 2: projections, W-amortized 2-phase -----------------
// Block = 128 X rows x 64 outcols, 4 waves. W panel 96KB staged ONCE
// (prologue, R6 layout/swizzle). X double-buffered supersteps of 64 floats
// (buf 128x256B = 32KB). LDS = 160KB dynamic. Sync = R8's counted
// vmcnt + raw s_barrier discipline. Ingest: 144MB X + 36MB W (was 290MB).
#define XB_OFF 98304    // W panel [0,96KB), X bufs at 98304 + buf*32768
#define PR_NSS 12       // 768 / 64

__device__ __forceinline__ void stage_x(const float* Xb, uint8_t* xbuf,
                                        int ss, int tid) {
  #pragma unroll
  for (int i = 0; i < 8; ++i) {
    int c   = i * 256 + tid;           // 16B chunk 0..2047
    int row = c >> 4;                  // 0..127
    int ch  = c & 15;
    int sch = (ch & 8) | ((ch & 7) ^ (row & 7));
    const float* src = Xb + (size_t)row * HID + ss * 64 + sch * 4;
    __builtin_amdgcn_global_load_lds((gptr_t)src, (lptr_t)(xbuf + c * 16), 16, 0, 0);
  }
}

__global__ __launch_bounds__(256) void proj_kernel(
    const float* __restrict__ qin, const float* __restrict__ kin,
    const float* __restrict__ vin, uint8_t* __restrict__ ws) {
  extern __shared__ __align__(16) uint8_t smem[];   // 160KB dynamic
  const int t = blockIdx.y;
  const float* X = (t == 0) ? qin : (t == 1) ? kin : vin;
  const bf16_t* wtb = (const bf16_t*)(ws + WT_OFF) + (size_t)t * HD * HID;
  const float* bias = (const float*)(ws + B_OFF) + t * HD;

  const int tid  = threadIdx.x;
  const int w    = tid >> 6;
  const int lane = tid & 63;
  const int lm   = lane & 15;
  const int kg   = lane >> 4;
  const int r0   = blockIdx.x * 128;

  const float* Xb = X + (size_t)r0 * HID;

  // ---- prologue: W panel (6144 chunks) + X ss0, ss1 ----
  #pragma unroll
  for (int j = 0; j < 24; ++j) {
    int g   = j * 256 + tid;
    int row = g / 96;                  // outcol 0..63
    int ci  = g % 96;                  // 16B chunk in 1536B row
    int swz = (ci & ~7) | ((ci & 7) ^ (row & 7));
    const bf16_t* src = wtb + (size_t)row * HID + swz * 8;
    __builtin_amdgcn_global_load_lds((gptr_t)src, (lptr_t)(smem + g * 16), 16, 0, 0);
  }
  stage_x(Xb, smem + XB_OFF,         0, tid);
  stage_x(Xb, smem + XB_OFF + 32768, 1, tid);
  __syncthreads();                     // drain: W + ss0 + ss1 ready

  f32x4 acc[2][4] = {{{0,0,0,0},{0,0,0,0},{0,0,0,0},{0,0,0,0}},
                     {{0,0,0,0},{0,0,0,0},{0,0,0,0},{0,0,0,0}}};

  #pragma unroll 1
  for (int ss = 0; ss < PR_NSS; ++ss) {
    if (ss > 0) {
      if (ss < PR_NSS - 1) { asm volatile("s_waitcnt vmcnt(8)" ::: "memory"); }
      else                 { asm volatile("s_waitcnt vmcnt(0)" ::: "memory"); }
      __builtin_amdgcn_sched_barrier(0);
      __builtin_amdgcn_s_barrier();
      __builtin_amdgcn_sched_barrier(0);
    }
    const uint8_t* xb = smem + XB_OFF + (ss & 1) * 32768;
    #pragma unroll
    for (int kstep = 0; kstep < 2; ++kstep) {
      int kk = ss * 2 + kstep;
      bf16x8 xv[2];
      #pragma unroll
      for (int rg = 0; rg < 2; ++rg) {
        int row = w * 32 + rg * 16 + lm;
        int c0  = kstep * 8 + ((2 * kg)     ^ (row & 7));
        int c1  = kstep * 8 + ((2 * kg + 1) ^ (row & 7));
        f32x4 x0 = *(const f32x4*)(xb + row * 256 + c0 * 16);
        f32x4 x1 = *(const f32x4*)(xb + row * 256 + c1 * 16);
        bf16x8 v;
        v[0] = (bf16_t)x0[0]; v[1] = (bf16_t)x0[1];
        v[2] = (bf16_t)x0[2]; v[3] = (bf16_t)x0[3];
        v[4] = (bf16_t)x1[0]; v[5] = (bf16_t)x1[1];
        v[6] = (bf16_t)x1[2]; v[7] = (bf16_t)x1[3];
        xv[rg] = v;
      }
      #pragma unroll
      for (int c = 0; c < 4; ++c) {
        int wrow = c * 16 + lm;
        int ci   = kk * 4 + kg;
        int swz  = (ci & ~7) | ((ci & 7) ^ (lm & 7));
        bf16x8 wf = *(const bf16x8*)(smem + wrow * 1536 + swz * 16);
        acc[0][c] = __builtin_amdgcn_mfma_f32_16x16x32_bf16(wf, xv[0], acc[0][c], 0, 0, 0);
        acc[1][c] = __builtin_amdgcn_mfma_f32_16x16x32_bf16(wf, xv[1], acc[1][c], 0, 0, 0);
      }
    }
    __builtin_amdgcn_s_barrier();      // all waves done reading this buf
    __builtin_amdgcn_sched_barrier(0);
    if (ss + 2 < PR_NSS)
      stage_x(Xb, smem + XB_OFF + (ss & 1) * 32768, ss + 2, tid);
  }

  // D: col(lane&15)=x_row, row(kg*4+j)=outcol within each 16-group
  #pragma unroll
  for (int rg = 0; rg < 2; ++rg) {
    const int r = r0 + w * 32 + rg * 16 + lm;
    if (t < 2) {
      bf16_t* out = (bf16_t*)(ws + Q_OFF) + (size_t)t * NB * SEQ * HD;
      #pragma unroll
      for (int c = 0; c < 4; ++c) {
        f32x4 b4 = *(const f32x4*)(bias + c * 16 + kg * 4);
        bf16x4 pk;
        pk[0] = (bf16_t)(acc[rg][c][0] + b4[0]);
        pk[1] = (bf16_t)(acc[rg][c][1] + b4[1]);
        pk[2] = (bf16_t)(acc[rg][c][2] + b4[2]);
        pk[3] = (bf16_t)(acc[rg][c][3] + b4[3]);
        *(bf16x4*)(out + (size_t)r * HD + c * 16 + kg * 4) = pk;
      }
    } else {
      // V^T panels: vt[b][s>>6][d][s&63]
      bf16_t* vt = (bf16_t*)(ws + V_OFF);
      const int bi = r >> 11;
      const int s  = r & 2047;
      bf16_t* pan = vt + ((size_t)(bi * 32 + (s >> 6))) * 4096 + (s & 63);
      #pragma unroll
      for (int c = 0; c < 4; ++c) {
        #pragma unroll
        for (int j = 0; j < 4; ++j) {
          int d = c * 16 + kg * 4 + j;
          pan[d * 64] = (bf16_t)(acc[rg][c][j] + bias[d]);
        }
      }
    }
  }
}

// ---------------- kernel 3: flash attention (LDS-staged, 2-phase) ------------
// (unchanged — V^T staged from contiguous panels)
__device__ __forceinline__ void stage_tiles(
    const bf16_t* kbase, const bf16_t* vtb, uint8_t* buf,
    int kvo, int s4, int lane) {
  const bf16_t* pan = vtb + (size_t)(kvo >> 6) * 4096;   // contiguous panel
  #pragma unroll
  for (int i = 0; i < 4; ++i) {
    int qi = s4 * 4 + i;               // 0..7 across the 2 waves of the group
    int r  = qi * 8 + (lane >> 3);     // row (K: kv row; V: d row)
    int c  = lane & 7;                 // 16B chunk within 128B row
    const bf16_t* gk = kbase + (size_t)(kvo + r) * HD + ((c ^ (r & 7)) * 8);
    __builtin_amdgcn_global_load_lds((gptr_t)gk, (lptr_t)(buf + qi * 1024), 16, 0, 0);
    const bf16_t* gv = pan + r * 64 + ((c ^ (r & 7)) * 8);
    __builtin_amdgcn_global_load_lds((gptr_t)gv, (lptr_t)(buf + 8192 + qi * 1024), 16, 0, 0);
  }
}

__global__ __launch_bounds__(256, 2) void attn_kernel(
    const uint8_t* __restrict__ ws, const int* __restrict__ mask,
    float* __restrict__ out) {
  __shared__ __align__(16) uint8_t smem[4 * 16384 + 512];
  const int blk  = blockIdx.x;
  const int b    = blk & 7;          // batch -> XCD (L2 locality)
  const int qt   = blk >> 3;         // q tile 0..63
  const int tid  = threadIdx.x;
  const int w    = tid >> 6;
  const int g4   = w >> 1;           // kv group
  const int s4   = w & 1;            // sub-wave in group
  const int lane = tid & 63;
  const int lm   = lane & 15;
  const int kg   = lane >> 4;

  const bf16_t* qb = (const bf16_t*)(ws + Q_OFF);
  const bf16_t* kbase = (const bf16_t*)(ws + K_OFF) + (size_t)b * SEQ * HD;
  const bf16_t* vtb = (const bf16_t*)(ws + V_OFF) + (size_t)b * HD * SEQ;
  const int* mp = mask + b * SEQ;

  const int qrow0 = b * SEQ + qt * 32;          // block's first q row
  const int qrw   = qrow0 + s4 * 16;            // this wave's 16 q rows
  bf16x8 qf0 = *(const bf16x8*)(qb + (size_t)(qrw + lm) * HD + kg * 8);
  bf16x8 qf1 = *(const bf16x8*)(qb + (size_t)(qrw + lm) * HD + 32 + kg * 8);

  f32x4 o[4] = {{0,0,0,0},{0,0,0,0},{0,0,0,0},{0,0,0,0}};
  float m_run = -1e30f;   // per-lane, q = lm (same across kg after reduce)
  float l_run = 0.f;

  uint8_t* mytiles = smem + g4 * 32768;         // 2 bufs x 16KB
  const int kv_lo = g4 * 1024;

  stage_tiles(kbase, vtb, mytiles, kv_lo, s4, lane);
  __syncthreads();                               // drains vmcnt -> buf0 ready

  #pragma unroll 1
  for (int it = 0; it < 16; ++it) {
    uint8_t* cur = mytiles + (it & 1) * 16384;
    uint8_t* nxt = mytiles + ((it & 1) ^ 1) * 16384;
    const int kvo = kv_lo + it * 64;
    if (it < 15) stage_tiles(kbase, vtb, nxt, kvo + 64, s4, lane);

    // mask loads (early, L2-hot)
    i32x4 mv[4];
    #pragma unroll
    for (int nf = 0; nf < 4; ++nf)
      mv[nf] = *(const i32x4*)(mp + kvo + nf * 16 + kg * 4);

    // ---- QK^T from LDS ----
    const uint8_t* Kb = cur;
    const uint8_t* Vb = cur + 8192;
    f32x4 sc[4];
    #pragma unroll
    for (int nf = 0; nf < 4; ++nf) {
      int r = nf * 16 + lm;
      bf16x8 k0 = *(const bf16x8*)(Kb + r * 128 + ((kg ^ (r & 7)) << 4));
      bf16x8 k1 = *(const bf16x8*)(Kb + r * 128 + (((4 + kg) ^ (r & 7)) << 4));
      f32x4 z = {0.f, 0.f, 0.f, 0.f};
      z = __builtin_amdgcn_mfma_f32_16x16x32_bf16(k0, qf0, z, 0, 0, 0);
      z = __builtin_amdgcn_mfma_f32_16x16x32_bf16(k1, qf1, z, 0, 0, 0);
      sc[nf] = z;   // P[kv = nf*16 + kg*4 + i][q = lm]
    }

    // ---- mask ----
    #pragma unroll
    for (int nf = 0; nf < 4; ++nf)
      #pragma unroll
      for (int i = 0; i < 4; ++i)
        if (mv[nf][i] == 0) sc[nf][i] = -1e30f;

    // ---- online softmax (per-lane scalars, q = lm) ----
    float pm = sc[0][0];
    #pragma unroll
    for (int nf = 0; nf < 4; ++nf)
      #pragma unroll
      for (int i = 0; i < 4; ++i) pm = fmaxf(pm, sc[nf][i]);
    pm = fmaxf(pm, __shfl_xor(pm, 16));
    pm = fmaxf(pm, __shfl_xor(pm, 32));
    float mn = fmaxf(m_run, pm);
    float corr = __builtin_amdgcn_exp2f(m_run - mn);
    m_run = mn;
    float s_loc = 0.f;
    #pragma unroll
    for (int nf = 0; nf < 4; ++nf)
      #pragma unroll
      for (int i = 0; i < 4; ++i) {
        float p = __builtin_amdgcn_exp2f(sc[nf][i] - mn);
        sc[nf][i] = p;
        s_loc += p;
      }
    s_loc += __shfl_xor(s_loc, 16);
    s_loc += __shfl_xor(s_loc, 32);
    l_run = l_run * corr + s_loc;
    #pragma unroll
    for (int nf2 = 0; nf2 < 4; ++nf2) {
      o[nf2][0] *= corr; o[nf2][1] *= corr; o[nf2][2] *= corr; o[nf2][3] *= corr;
    }

    // ---- pack P B-frags ----
    bf16x8 pb[2];
    #pragma unroll
    for (int h = 0; h < 2; ++h) {
      bf16x8 p8;
      p8[0] = (bf16_t)sc[2 * h][0];     p8[1] = (bf16_t)sc[2 * h][1];
      p8[2] = (bf16_t)sc[2 * h][2];     p8[3] = (bf16_t)sc[2 * h][3];
      p8[4] = (bf16_t)sc[2 * h + 1][0]; p8[5] = (bf16_t)sc[2 * h + 1][1];
      p8[6] = (bf16_t)sc[2 * h + 1][2]; p8[7] = (bf16_t)sc[2 * h + 1][3];
      pb[h] = p8;
    }

    // ---- PV: V^T A-frags from LDS (b64 granules, swizzled) ----
    #pragma unroll
    for (int nf2 = 0; nf2 < 4; ++nf2) {
      int d = nf2 * 16 + lm;
      #pragma unroll
      for (int h2 = 0; h2 < 2; ++h2) {
        int B1 = 8 * kg + 64 * h2;
        int B2 = B1 + 32;
        union { bf16x8 v8; bf16x4 v4[2]; } u;
        u.v4[0] = *(const bf16x4*)(Vb + d * 128 + (((B1 >> 4) ^ (d & 7)) << 4) + (B1 & 15));
        u.v4[1] = *(const bf16x4*)(Vb + d * 128 + (((B2 >> 4) ^ (d & 7)) << 4) + (B2 & 15));
        o[nf2] = __builtin_amdgcn_mfma_f32_16x16x32_bf16(u.v8, pb[h2], o[nf2], 0, 0, 0);
      }
    }
    __syncthreads();   // drains stage vmcnt; releases cur for restaging
  }

  // ---- partials to LDS (overlay on tile region) ----
  float* lds_o  = (float*)smem;                  // [4][64][17]
  float* lds_ml = (float*)(smem + 4 * 16384);    // [4][16][2]
  #pragma unroll
  for (int nf2 = 0; nf2 < 4; ++nf2)
    #pragma unroll
    for (int i = 0; i < 4; ++i)
      lds_o[(w * 64 + nf2 * 16 + kg * 4 + i) * 17 + lm] = o[nf2][i];
  if (lane < 16) {
    lds_ml[(w * 16 + lane) * 2 + 0] = m_run;
    lds_ml[(w * 16 + lane) * 2 + 1] = l_run;
  }
  __syncthreads();

  // ---- combine the 2 kv-groups, store fp32 ----
  {
    const int row = tid >> 3;        // 0..31
    const int d0  = (tid & 7) * 8;
    const int s   = row >> 4, lmq = row & 15;
    const int w1  = s, w2 = 2 + s;   // wave ids (g0,s) and (g1,s)
    float m1 = lds_ml[(w1 * 16 + lmq) * 2], l1 = lds_ml[(w1 * 16 + lmq) * 2 + 1];
    float m2 = lds_ml[(w2 * 16 + lmq) * 2], l2 = lds_ml[(w2 * 16 + lmq) * 2 + 1];
    float mt = fmaxf(m1, m2);
    float f1 = __builtin_amdgcn_exp2f(m1 - mt);
    float f2 = __builtin_amdgcn_exp2f(m2 - mt);
    float rden = 1.0f / (l1 * f1 + l2 * f2);
    float res[8];
    #pragma unroll
    for (int j = 0; j < 8; ++j) {
      float n1 = lds_o[(w1 * 64 + d0 + j) * 17 + lmq];
      float n2 = lds_o[(w2 * 64 + d0 + j) * 17 + lmq];
      res[j] = (n1 * f1 + n2 * f2) * rden;
    }
    float* op = out + (size_t)(qrow0 + row) * HD + d0;
    *(f32x4*)op = *(f32x4*)&res[0];
    *(f32x4*)(op + 4) = *(f32x4*)&res[4];
  }
}

extern "C" void kernel_launch(void* const* d_in, const int* in_sizes, int n_in,
                              void* d_out, int out_size, void* d_ws, size_t ws_size,
                              hipStream_t stream) {
  const float* q  = (const float*)d_in[0];
  const float* k  = (const float*)d_in[1];
  const float* v  = (const float*)d_in[2];
  const int* mask = (const int*)d_in[3];
  const float* Wq = (const float*)d_in[4];
  const float* bq = (const float*)d_in[5];
  const float* Wk = (const float*)d_in[6];
  const float* bk = (const float*)d_in[7];
  const float* Wv = (const float*)d_in[8];
  const float* bv = (const float*)d_in[9];
  uint8_t* ws = (uint8_t*)d_ws;
  float* out  = (float*)d_out;
  if (ws_size < WS_NEED) return;   // need ~6.7 MB scratch

  hipLaunchKernelGGL(cvt_kernel, dim3(576), dim3(256), 0, stream,
                     Wq, bq, Wk, bk, Wv, bv, ws);
  hipLaunchKernelGGL(proj_kernel, dim3(128, 3), dim3(256), 163840, stream,
                     q, k, v, ws);
  hipLaunchKernelGGL(attn_kernel, dim3(NB * SEQ / 32), dim3(256), 0, stream,
                     ws, mask, out);
}

// Round 14
// 60.660 us; speedup vs baseline: 1.1369x; 1.1369x over previous
//
#include <hip/hip_runtime.h>
#include <stdint.h>

#define HID 768
#define HD  64
#define NB  8
#define SEQ 2048

typedef __bf16 bf16_t;
typedef __bf16 bf16x8 __attribute__((ext_vector_type(8)));
typedef __bf16 bf16x4 __attribute__((ext_vector_type(4)));
typedef float  f32x4  __attribute__((ext_vector_type(4)));
typedef int    i32x4  __attribute__((ext_vector_type(4)));

typedef const __attribute__((address_space(1))) uint32_t* gptr_t;
typedef __attribute__((address_space(3))) uint32_t* lptr_t;

// workspace layout (bytes)
#define WT_OFF 0                         // bf16 WT[3][64][768]
#define B_OFF  (3*HD*HID*2)              // f32  bias[3][64]
#define Q_OFF  (512*1024)                // bf16 q[16384][64]   (row-major)
#define K_OFF  (Q_OFF + NB*SEQ*HD*2)     // bf16 k[16384][64]   (row-major)
#define V_OFF  (K_OFF + NB*SEQ*HD*2)     // bf16 vt[8][64][2048] (TRANSPOSED)
#define WS_NEED ((size_t)(V_OFF + NB*SEQ*HD*2))

#define ALPHA 0.18033688011112043f       // log2(e) / sqrt(64)

// ---------------- kernel 1: convert + transpose weights, fold scale ----------
__global__ __launch_bounds__(256) void cvt_kernel(
    const float* __restrict__ Wq, const float* __restrict__ bq,
    const float* __restrict__ Wk, const float* __restrict__ bk,
    const float* __restrict__ Wv, const float* __restrict__ bv,
    uint8_t* __restrict__ ws) {
  bf16_t* wt = (bf16_t*)(ws + WT_OFF);
  float*  bs = (float*)(ws + B_OFF);
  int idx = blockIdx.x * 256 + threadIdx.x;
  if (idx < 3 * HID * HD) {
    int n = idx & 63;
    int h = (idx >> 6) % HID;
    int t = idx / (HID * HD);
    const float* W = (t == 0) ? Wq : (t == 1) ? Wk : Wv;
    float v = W[h * HD + n];
    if (t == 0) v *= ALPHA;                    // prescale q path
    wt[(size_t)(t * HD + n) * HID + h] = (bf16_t)v;   // WT[t][n][h]
  }
  if (idx < 3 * HD) {
    int t = idx / HD, n = idx % HD;
    const float* bsrc = (t == 0) ? bq : (t == 1) ? bk : bv;
    bs[idx] = bsrc[n] * ((t == 0) ? ALPHA : 1.0f);
  }
}

// ---------------- kernel 2: projections, m97-style LDS 2-phase ---------------
// Block = 64 X rows x 64 out cols, 4 waves. Per K-step (32 floats):
// X chunk 64x32 fp32 (8KB) + W chunk 64x32 bf16 (4KB), double-buffered,
// staged via global_load_lds w16 (LDS dest linear, SOURCE pre-swizzled with
// the same chunk-XOR used on the read side).
__device__ __forceinline__ void stage_x(const float* Xb, uint8_t* dst,
                                        int w, int lane) {
  #pragma unroll
  for (int j = 0; j < 2; ++j) {
    int cb  = j * 256 + w * 64;          // wave-uniform chunk base
    int row = (cb + lane) >> 3;          // 0..63
    int c8  = lane & 7;                  // 16B chunk in 128B row
    const float* src = Xb + (size_t)row * HID + ((c8 ^ (row & 7)) * 4);
    __builtin_amdgcn_global_load_lds((gptr_t)src, (lptr_t)(dst + cb * 16), 16, 0, 0);
  }
}
__device__ __forceinline__ void stage_w(const bf16_t* Wb, uint8_t* dst,
                                        int w, int lane) {
  int cb  = w * 64;
  int row = (cb + lane) >> 2;            // out col 0..63
  int c4  = lane & 3;                    // 16B chunk in 64B row
  const bf16_t* src = Wb + (size_t)row * HID + ((c4 ^ (row & 3)) * 8);
  __builtin_amdgcn_global_load_lds((gptr_t)src, (lptr_t)(dst + cb * 16), 16, 0, 0);
}

__global__ __launch_bounds__(256, 4) void proj_kernel(
    const float* __restrict__ qin, const float* __restrict__ kin,
    const float* __restrict__ vin, uint8_t* __restrict__ ws) {
  __shared__ __align__(16) uint8_t smem[2 * 8192 + 2 * 4096];
  const int t = blockIdx.y;
  const float* X = (t == 0) ? qin : (t == 1) ? kin : vin;
  const bf16_t* wt = (const bf16_t*)(ws + WT_OFF) + (size_t)t * HD * HID;
  const float* bias = (const float*)(ws + B_OFF) + t * HD;

  const int tid  = threadIdx.x;
  const int wid  = tid >> 6;
  const int lane = tid & 63;
  const int lm   = lane & 15;
  const int kg   = lane >> 4;
  const int r0   = blockIdx.x * 64;

  const float* Xrow = X + (size_t)r0 * HID;

  f32x4 acc[4] = {{0,0,0,0},{0,0,0,0},{0,0,0,0},{0,0,0,0}};

  stage_x(Xrow, smem, wid, lane);
  stage_w(wt, smem + 16384, wid, lane);
  __syncthreads();                        // drains vmcnt -> buf0 ready

  const int xrow = wid * 16 + lm;         // this lane's X row in LDS
  #pragma unroll 1
  for (int kk = 0; kk < 24; ++kk) {
    uint8_t* xcur = smem + (kk & 1) * 8192;
    uint8_t* wcur = smem + 16384 + (kk & 1) * 4096;
    if (kk < 23) {
      stage_x(Xrow + (kk + 1) * 32, smem + ((kk + 1) & 1) * 8192, wid, lane);
      stage_w(wt + (kk + 1) * 32, smem + 16384 + ((kk + 1) & 1) * 4096, wid, lane);
    }
    // W A-frags from LDS (row = out col c*16+lm, chunk = kg, swizzled)
    bf16x8 wf[4];
    #pragma unroll
    for (int c = 0; c < 4; ++c) {
      int row = c * 16 + lm;
      wf[c] = *(const bf16x8*)(wcur + row * 64 + ((kg ^ (lm & 3)) << 4));
    }
    // X B-frag from LDS (row = xrow, chunks 2kg, 2kg+1, swizzled)
    f32x4 x0 = *(const f32x4*)(xcur + xrow * 128 + (((kg * 2) ^ (lm & 7)) << 4));
    f32x4 x1 = *(const f32x4*)(xcur + xrow * 128 + (((kg * 2 + 1) ^ (lm & 7)) << 4));
    bf16x8 v;
    v[0] = (bf16_t)x0[0]; v[1] = (bf16_t)x0[1];
    v[2] = (bf16_t)x0[2]; v[3] = (bf16_t)x0[3];
    v[4] = (bf16_t)x1[0]; v[5] = (bf16_t)x1[1];
    v[6] = (bf16_t)x1[2]; v[7] = (bf16_t)x1[3];
    #pragma unroll
    for (int c = 0; c < 4; ++c)
      acc[c] = __builtin_amdgcn_mfma_f32_16x16x32_bf16(wf[c], v, acc[c], 0, 0, 0);
    __syncthreads();                      // stage(kk+1) complete; release bufs
  }

  // D: col(lane&15)=x_row, row((lane>>4)*4+reg)=out_col
  if (t < 2) {
    bf16_t* out = (bf16_t*)(ws + Q_OFF) + (size_t)t * NB * SEQ * HD;
    #pragma unroll
    for (int c = 0; c < 4; ++c) {
      f32x4 b4 = *(const f32x4*)(bias + c * 16 + kg * 4);
      bf16x4 pk;
      pk[0] = (bf16_t)(acc[c][0] + b4[0]);
      pk[1] = (bf16_t)(acc[c][1] + b4[1]);
      pk[2] = (bf16_t)(acc[c][2] + b4[2]);
      pk[3] = (bf16_t)(acc[c][3] + b4[3]);
      *(bf16x4*)(out + (size_t)(r0 + wid * 16 + lm) * HD + c * 16 + kg * 4) = pk;
    }
  } else {
    // V transposed: vt[b][d][s]
    bf16_t* vt = (bf16_t*)(ws + V_OFF);
    const int r  = r0 + wid * 16 + lm;
    const int bi = r >> 11;
    const int s  = r & 2047;
    #pragma unroll
    for (int c = 0; c < 4; ++c) {
      f32x4 b4 = *(const f32x4*)(bias + c * 16 + kg * 4);
      #pragma unroll
      for (int j = 0; j < 4; ++j) {
        int d = c * 16 + kg * 4 + j;
        vt[((size_t)(bi * HD + d)) * SEQ + s] = (bf16_t)(acc[c][j] + b4[j]);
      }
    }
  }
}

// ---------------- kernel 3: flash attention (LDS-staged, 2-phase) ------------
__device__ __forceinline__ void stage_tiles(
    const bf16_t* kbase, const bf16_t* vtb, uint8_t* buf,
    int kvo, int s4, int lane) {
  #pragma unroll
  for (int i = 0; i < 4; ++i) {
    int qi = s4 * 4 + i;               // 0..7 across the 2 waves of the group
    int r  = qi * 8 + (lane >> 3);     // row (K: kv row; V: d row)
    int c  = lane & 7;                 // 16B chunk within 128B row
    const bf16_t* gk = kbase + (size_t)(kvo + r) * HD + ((c ^ (r & 7)) * 8);
    __builtin_amdgcn_global_load_lds((gptr_t)gk, (lptr_t)(buf + qi * 1024), 16, 0, 0);
    const bf16_t* gv = vtb + (size_t)r * SEQ + kvo + ((c ^ (r & 7)) * 8);
    __builtin_amdgcn_global_load_lds((gptr_t)gv, (lptr_t)(buf + 8192 + qi * 1024), 16, 0, 0);
  }
}

__global__ __launch_bounds__(256, 2) void attn_kernel(
    const uint8_t* __restrict__ ws, const int* __restrict__ mask,
    float* __restrict__ out) {
  __shared__ __align__(16) uint8_t smem[4 * 16384 + 512];
  const int blk  = blockIdx.x;
  const int b    = blk & 7;          // batch -> XCD (L2 locality)
  const int qt   = blk >> 3;         // q tile 0..63
  const int tid  = threadIdx.x;
  const int w    = tid >> 6;
  const int g4   = w >> 1;           // kv group
  const int s4   = w & 1;            // sub-wave in group
  const int lane = tid & 63;
  const int lm   = lane & 15;
  const int kg   = lane >> 4;

  const bf16_t* qb = (const bf16_t*)(ws + Q_OFF);
  const bf16_t* kbase = (const bf16_t*)(ws + K_OFF) + (size_t)b * SEQ * HD;
  const bf16_t* vtb = (const bf16_t*)(ws + V_OFF) + (size_t)b * HD * SEQ;
  const int* mp = mask + b * SEQ;

  const int qrow0 = b * SEQ + qt * 32;          // block's first q row
  const int qrw   = qrow0 + s4 * 16;            // this wave's 16 q rows
  bf16x8 qf0 = *(const bf16x8*)(qb + (size_t)(qrw + lm) * HD + kg * 8);
  bf16x8 qf1 = *(const bf16x8*)(qb + (size_t)(qrw + lm) * HD + 32 + kg * 8);

  f32x4 o[4] = {{0,0,0,0},{0,0,0,0},{0,0,0,0},{0,0,0,0}};
  float m_run = -1e30f;   // per-lane, q = lm (same across kg after reduce)
  float l_run = 0.f;

  uint8_t* mytiles = smem + g4 * 32768;         // 2 bufs x 16KB
  const int kv_lo = g4 * 1024;

  stage_tiles(kbase, vtb, mytiles, kv_lo, s4, lane);
  __syncthreads();                               // drains vmcnt -> buf0 ready

  #pragma unroll 1
  for (int it = 0; it < 16; ++it) {
    uint8_t* cur = mytiles + (it & 1) * 16384;
    uint8_t* nxt = mytiles + ((it & 1) ^ 1) * 16384;
    const int kvo = kv_lo + it * 64;
    if (it < 15) stage_tiles(kbase, vtb, nxt, kvo + 64, s4, lane);

    // mask loads (early, L2-hot)
    i32x4 mv[4];
    #pragma unroll
    for (int nf = 0; nf < 4; ++nf)
      mv[nf] = *(const i32x4*)(mp + kvo + nf * 16 + kg * 4);

    // ---- QK^T from LDS ----
    const uint8_t* Kb = cur;
    const uint8_t* Vb = cur + 8192;
    f32x4 sc[4];
    #pragma unroll
    for (int nf = 0; nf < 4; ++nf) {
      int r = nf * 16 + lm;
      bf16x8 k0 = *(const bf16x8*)(Kb + r * 128 + ((kg ^ (r & 7)) << 4));
      bf16x8 k1 = *(const bf16x8*)(Kb + r * 128 + (((4 + kg) ^ (r & 7)) << 4));
      f32x4 z = {0.f, 0.f, 0.f, 0.f};
      z = __builtin_amdgcn_mfma_f32_16x16x32_bf16(k0, qf0, z, 0, 0, 0);
      z = __builtin_amdgcn_mfma_f32_16x16x32_bf16(k1, qf1, z, 0, 0, 0);
      sc[nf] = z;   // P[kv = nf*16 + kg*4 + i][q = lm]
    }

    // ---- mask ----
    #pragma unroll
    for (int nf = 0; nf < 4; ++nf)
      #pragma unroll
      for (int i = 0; i < 4; ++i)
        if (mv[nf][i] == 0) sc[nf][i] = -1e30f;

    // ---- online softmax (per-lane scalars, q = lm) ----
    float pm = sc[0][0];
    #pragma unroll
    for (int nf = 0; nf < 4; ++nf)
      #pragma unroll
      for (int i = 0; i < 4; ++i) pm = fmaxf(pm, sc[nf][i]);
    pm = fmaxf(pm, __shfl_xor(pm, 16));
    pm = fmaxf(pm, __shfl_xor(pm, 32));
    float mn = fmaxf(m_run, pm);
    float corr = __builtin_amdgcn_exp2f(m_run - mn);
    m_run = mn;
    float s_loc = 0.f;
    #pragma unroll
    for (int nf = 0; nf < 4; ++nf)
      #pragma unroll
      for (int i = 0; i < 4; ++i) {
        float p = __builtin_amdgcn_exp2f(sc[nf][i] - mn);
        sc[nf][i] = p;
        s_loc += p;
      }
    s_loc += __shfl_xor(s_loc, 16);
    s_loc += __shfl_xor(s_loc, 32);
    l_run = l_run * corr + s_loc;
    #pragma unroll
    for (int nf2 = 0; nf2 < 4; ++nf2) {
      o[nf2][0] *= corr; o[nf2][1] *= corr; o[nf2][2] *= corr; o[nf2][3] *= corr;
    }

    // ---- pack P B-frags ----
    bf16x8 pb[2];
    #pragma unroll
    for (int h = 0; h < 2; ++h) {
      bf16x8 p8;
      p8[0] = (bf16_t)sc[2 * h][0];     p8[1] = (bf16_t)sc[2 * h][1];
      p8[2] = (bf16_t)sc[2 * h][2];     p8[3] = (bf16_t)sc[2 * h][3];
      p8[4] = (bf16_t)sc[2 * h + 1][0]; p8[5] = (bf16_t)sc[2 * h + 1][1];
      p8[6] = (bf16_t)sc[2 * h + 1][2]; p8[7] = (bf16_t)sc[2 * h + 1][3];
      pb[h] = p8;
    }

    // ---- PV: V^T A-frags from LDS (b64 granules, swizzled) ----
    #pragma unroll
    for (int nf2 = 0; nf2 < 4; ++nf2) {
      int d = nf2 * 16 + lm;
      #pragma unroll
      for (int h2 = 0; h2 < 2; ++h2) {
        int B1 = 8 * kg + 64 * h2;
        int B2 = B1 + 32;
        union { bf16x8 v8; bf16x4 v4[2]; } u;
        u.v4[0] = *(const bf16x4*)(Vb + d * 128 + (((B1 >> 4) ^ (d & 7)) << 4) + (B1 & 15));
        u.v4[1] = *(const bf16x4*)(Vb + d * 128 + (((B2 >> 4) ^ (d & 7)) << 4) + (B2 & 15));
        o[nf2] = __builtin_amdgcn_mfma_f32_16x16x32_bf16(u.v8, pb[h2], o[nf2], 0, 0, 0);
      }
    }
    __syncthreads();   // drains stage vmcnt; releases cur for restaging
  }

  // ---- partials to LDS (overlay on tile region) ----
  float* lds_o  = (float*)smem;                  // [4][64][17]
  float* lds_ml = (float*)(smem + 4 * 16384);    // [4][16][2]
  #pragma unroll
  for (int nf2 = 0; nf2 < 4; ++nf2)
    #pragma unroll
    for (int i = 0; i < 4; ++i)
      lds_o[(w * 64 + nf2 * 16 + kg * 4 + i) * 17 + lm] = o[nf2][i];
  if (lane < 16) {
    lds_ml[(w * 16 + lane) * 2 + 0] = m_run;
    lds_ml[(w * 16 + lane) * 2 + 1] = l_run;
  }
  __syncthreads();

  // ---- combine the 2 kv-groups, store fp32 ----
  {
    const int row = tid >> 3;        // 0..31
    const int d0  = (tid & 7) * 8;
    const int s   = row >> 4, lmq = row & 15;
    const int w1  = s, w2 = 2 + s;   // wave ids (g0,s) and (g1,s)
    float m1 = lds_ml[(w1 * 16 + lmq) * 2], l1 = lds_ml[(w1 * 16 + lmq) * 2 + 1];
    float m2 = lds_ml[(w2 * 16 + lmq) * 2], l2 = lds_ml[(w2 * 16 + lmq) * 2 + 1];
    float mt = fmaxf(m1, m2);
    float f1 = __builtin_amdgcn_exp2f(m1 - mt);
    float f2 = __builtin_amdgcn_exp2f(m2 - mt);
    float rden = 1.0f / (l1 * f1 + l2 * f2);
    float res[8];
    #pragma unroll
    for (int j = 0; j < 8; ++j) {
      float n1 = lds_o[(w1 * 64 + d0 + j) * 17 + lmq];
      float n2 = lds_o[(w2 * 64 + d0 + j) * 17 + lmq];
      res[j] = (n1 * f1 + n2 * f2) * rden;
    }
    float* op = out + (size_t)(qrow0 + row) * HD + d0;
    *(f32x4*)op = *(f32x4*)&res[0];
    *(f32x4*)(op + 4) = *(f32x4*)&res[4];
  }
}

extern "C" void kernel_launch(void* const* d_in, const int* in_sizes, int n_in,
                              void* d_out, int out_size, void* d_ws, size_t ws_size,
                              hipStream_t stream) {
  const float* q  = (const float*)d_in[0];
  const float* k  = (const float*)d_in[1];
  const float* v  = (const float*)d_in[2];
  const int* mask = (const int*)d_in[3];
  const float* Wq = (const float*)d_in[4];
  const float* bq = (const float*)d_in[5];
  const float* Wk = (const float*)d_in[6];
  const float* bk = (const float*)d_in[7];
  const float* Wv = (const float*)d_in[8];
  const float* bv = (const float*)d_in[9];
  uint8_t* ws = (uint8_t*)d_ws;
  float* out  = (float*)d_out;
  if (ws_size < WS_NEED) return;   // need ~6.7 MB scratch

  hipLaunchKernelGGL(cvt_kernel, dim3(576), dim3(256), 0, stream,
                     Wq, bq, Wk, bk, Wv, bv, ws);
  hipLaunchKernelGGL(proj_kernel, dim3(256, 3), dim3(256), 0, stream,
                     q, k, v, ws);
  hipLaunchKernelGGL(attn_kernel, dim3(NB * SEQ / 32), dim3(256), 0, stream,
                     ws, mask, out);
}